// Round 15
// baseline (276.214 us; speedup 1.0000x reference)
//
#include <hip/hip_runtime.h>
#include <math.h>

#define SEQ 4096
#define DIM 1024
#define HEADS 8
#define DINNER 512
#define QKVW 1536
#define PAD 80   // LDS row stride (bf16 elems) for legacy fallback kernels
#define CHUNK 16 // K-tiles (of 64) per split-KV chunk

typedef unsigned short u16;
typedef __attribute__((ext_vector_type(8))) short s8v;   // 8 bf16 (4 VGPRs)
typedef __attribute__((ext_vector_type(4))) float f4v;   // 4 fp32 acc
#define MFMA(a, b, c) __builtin_amdgcn_mfma_f32_16x16x32_bf16(a, b, c, 0, 0, 0)

__device__ __forceinline__ u16 f2bf(float f) {
    unsigned u = __float_as_uint(f);
    u += 0x7fff + ((u >> 16) & 1);   // RNE
    return (u16)(u >> 16);
}
__device__ __forceinline__ float bf2f(u16 b) { return __uint_as_float(((unsigned)b) << 16); }

// async global->LDS, 16B per lane. LDS dest is wave-uniform base + lane*16 (HW rule);
// the GLOBAL source is per-lane and pre-swizzled to realize the LDS XOR swizzle (rule #21).
__device__ __forceinline__ void gload16(const u16* g, u16* l) {
    __builtin_amdgcn_global_load_lds(
        (const __attribute__((address_space(1))) unsigned int*)g,
        (__attribute__((address_space(3))) unsigned int*)l, 16, 0, 0);
}

// chunk-tile flat index: T = h*160 + base16(qt) + c; nc(qt) = qt/16 + 1
__device__ __forceinline__ int base16(int qt) {
    int a = qt >> 4, b = qt & 15;
    return 8 * a * (a + 1) + b * (a + 1);
}
// partials: tiles 0..1023 in d_out, 1024..1279 in the dead wqt region
__device__ __forceinline__ float* po_sel(int T, float* pd, float* pw) {
    return (T < 1024) ? pd + (size_t)T * 4096 : pw + (size_t)(T - 1024) * 4096;
}

// ---------- RMSNorm -> split bf16 (hi, lo), vectorized (G13) ----------
__global__ __launch_bounds__(256) void rmsnorm_split(const float* __restrict__ x,
                                                     const float* __restrict__ gamma,
                                                     u16* __restrict__ hi,
                                                     u16* __restrict__ lo) {
    __shared__ float red[4];
    const int row = blockIdx.x, t = threadIdx.x;
    const float4 xv = ((const float4*)(x + (size_t)row * DIM))[t];
    float ss = xv.x * xv.x + xv.y * xv.y + xv.z * xv.z + xv.w * xv.w;
#pragma unroll
    for (int off = 32; off >= 1; off >>= 1) ss += __shfl_xor(ss, off, 64);
    if ((t & 63) == 0) red[t >> 6] = ss;
    __syncthreads();
    float scale = 32.0f / fmaxf(sqrtf(red[0] + red[1] + red[2] + red[3]), 1e-12f);
    const float4 gv = ((const float4*)gamma)[t];
    float y[4] = {xv.x * scale * gv.x, xv.y * scale * gv.y,
                  xv.z * scale * gv.z, xv.w * scale * gv.w};
    unsigned hw0, hw1, lw0, lw1;
    {
        u16 h0 = f2bf(y[0]), h1 = f2bf(y[1]), h2 = f2bf(y[2]), h3 = f2bf(y[3]);
        hw0 = (unsigned)h0 | ((unsigned)h1 << 16);
        hw1 = (unsigned)h2 | ((unsigned)h3 << 16);
        lw0 = (unsigned)f2bf(y[0] - bf2f(h0)) | ((unsigned)f2bf(y[1] - bf2f(h1)) << 16);
        lw1 = (unsigned)f2bf(y[2] - bf2f(h2)) | ((unsigned)f2bf(y[3] - bf2f(h3)) << 16);
    }
    *(uint2*)&hi[(size_t)row * DIM + t * 4] = make_uint2(hw0, hw1);
    *(uint2*)&lo[(size_t)row * DIM + t * 4] = make_uint2(lw0, lw1);
}

// ---------- transpose fp32 [R][C] -> bf16 hi/lo [C][R] ----------
__global__ __launch_bounds__(256) void transpose_split(const float* __restrict__ in,
                                                       u16* __restrict__ hi,
                                                       u16* __restrict__ lo,
                                                       int R, int C, int want_lo) {
    __shared__ float tile[64][65];
    const int c0 = blockIdx.x * 64, r0 = blockIdx.y * 64;
    const int t = threadIdx.x, col = t & 63, rb = t >> 6;
#pragma unroll
    for (int j = 0; j < 16; ++j)
        tile[rb + j * 4][col] = in[(size_t)(r0 + rb + j * 4) * C + c0 + col];
    __syncthreads();
#pragma unroll
    for (int j = 0; j < 16; ++j) {
        int cc = rb + j * 4;
        float v = tile[col][cc];
        size_t oi = (size_t)(c0 + cc) * R + r0 + col;
        u16 h = f2bf(v);
        hi[oi] = h;
        if (want_lo) lo[oi] = f2bf(v - bf2f(h));
    }
}

// ---------- QKV GEMM: 64x128 tile, 768 blocks = EXACTLY 3/CU, gload_lds + XOR swizzle ----------
// Mirror of the R4-verified 128x64 kernel with A/B roles swapped: 256 thr, 4 waves in
// 2(M) x 2(N), each wave 32x64 (acc[2][4]). LDS 48KB (A 2x8KB + B 2x16KB) -> 3 blocks/CU,
// 12 waves/CU across 3 INDEPENDENT blocks (better barrier overlap than 1.5x 8-wave blocks;
// R14's 384-block grid had 33% makespan waste from 1.5 blocks/CU imbalance).
__global__ __launch_bounds__(256) void gemm_qkv_64x128(
    const u16* __restrict__ Ah, const u16* __restrict__ Al,
    const u16* __restrict__ Bh, const u16* __restrict__ Bl,
    u16* __restrict__ qh, u16* __restrict__ ql,
    u16* __restrict__ kh, u16* __restrict__ kl, u16* __restrict__ vtp) {
    __shared__ __align__(16) u16 AsH[64 * 64], AsL[64 * 64];
    __shared__ __align__(16) u16 BsH[128 * 64], BsL[128 * 64];
    const int t = threadIdx.x;
    const int bn = blockIdx.x * 128, bm = blockIdx.y * 64;
    const int w = t >> 6, lane = t & 63, m = lane & 15, q = lane >> 4;
    const int wr = w >> 1, wc = w & 1;   // 2(M) x 2(N) wave grid; wave = 32 x 64
    f4v acc[2][4];
#pragma unroll
    for (int i = 0; i < 2; ++i)
#pragma unroll
        for (int j = 0; j < 4; ++j) acc[i][j] = (f4v){0.f, 0.f, 0.f, 0.f};

    for (int k0 = 0; k0 < DIM; k0 += 64) {
        __syncthreads();
        // B: 128x64 = 1024 granules (4 passes); A: 64x64 = 512 granules (2 passes)
#pragma unroll
        for (int i = 0; i < 4; ++i) {
            int idx0 = i * 256 + w * 64;              // wave-uniform LDS granule base
            int row = (idx0 + lane) >> 3;
            int col = ((lane & 7) * 8) ^ ((row & 7) * 8);   // pre-swizzled source column
            gload16(&Bh[(size_t)(bn + row) * DIM + k0 + col], &BsH[idx0 * 8]);
            gload16(&Bl[(size_t)(bn + row) * DIM + k0 + col], &BsL[idx0 * 8]);
            if (i < 2) {
                gload16(&Ah[(size_t)(bm + row) * DIM + k0 + col], &AsH[idx0 * 8]);
                gload16(&Al[(size_t)(bm + row) * DIM + k0 + col], &AsL[idx0 * 8]);
            }
        }
        __syncthreads();   // compiler drains vmcnt(0) here
#pragma unroll
        for (int kk = 0; kk < 64; kk += 32) {
            s8v a_h[2], a_l[2], b_h[4], b_l[4];
#pragma unroll
            for (int f = 0; f < 2; ++f) {
                int ar = wr * 32 + f * 16 + m;
                int ab = ar * 128 + (((kk + q * 8) * 2) ^ ((ar & 7) << 4));
                a_h[f] = *(const s8v*)((const char*)AsH + ab);
                a_l[f] = *(const s8v*)((const char*)AsL + ab);
            }
#pragma unroll
            for (int f = 0; f < 4; ++f) {
                int br = wc * 64 + f * 16 + m;
                int bb = br * 128 + (((kk + q * 8) * 2) ^ ((br & 7) << 4));
                b_h[f] = *(const s8v*)((const char*)BsH + bb);
                b_l[f] = *(const s8v*)((const char*)BsL + bb);
            }
#pragma unroll
            for (int fm = 0; fm < 2; ++fm)
#pragma unroll
                for (int fn = 0; fn < 4; ++fn) {
                    acc[fm][fn] = MFMA(a_h[fm], b_h[fn], acc[fm][fn]);
                    acc[fm][fn] = MFMA(a_l[fm], b_h[fn], acc[fm][fn]);
                    acc[fm][fn] = MFMA(a_h[fm], b_l[fn], acc[fm][fn]);
                }
        }
    }
    const int region = bn >> 9;   // uniform per block (bn mult of 128; bounds at 512/1024)
#pragma unroll
    for (int fm = 0; fm < 2; ++fm)
#pragma unroll
        for (int fn = 0; fn < 4; ++fn)
#pragma unroll
            for (int r = 0; r < 4; ++r) {
                int gr = bm + wr * 32 + fm * 16 + q * 4 + r;
                int gc = bn + wc * 64 + fn * 16 + m;
                float v = acc[fm][fn][r];
                if (region == 0) {
                    v *= 8.0f;   // q * sqrt(d), faithful to reference
                    u16 h = f2bf(v);
                    qh[(size_t)gr * DINNER + gc] = h;
                    ql[(size_t)gr * DINNER + gc] = f2bf(v - bf2f(h));
                } else if (region == 1) {
                    u16 h = f2bf(v);
                    kh[(size_t)gr * DINNER + (gc - 512)] = h;
                    kl[(size_t)gr * DINNER + (gc - 512)] = f2bf(v - bf2f(h));
                } else {
                    vtp[(size_t)(gc - 1024) * SEQ + gr] = f2bf(v);
                }
            }
}

// ---------- split-KV flash attention: 16 WAVES SHARE ONE STAGED K/V TILE (R13) ----------
__global__ __launch_bounds__(1024) void attn_chunk(
    const u16* __restrict__ qhp, const u16* __restrict__ qlp,
    const u16* __restrict__ kh, const u16* __restrict__ kl,
    const u16* __restrict__ vt,
    float* __restrict__ po_dout, float* __restrict__ po_wqt,
    float* __restrict__ ml) {
    __shared__ __align__(16) u16 KH[2][64 * 64], KL[2][64 * 64], VT[2][64 * 64];
    __shared__ __align__(16) u16 Pex[2][64 * 64];
    const int t = threadIdx.x;
    const int bx = blockIdx.x;
    const int qt4 = 15 - (bx >> 2), c = bx & 3, h = blockIdx.y;
    const int qtMax = 4 * qt4 + 3;
    if (c * CHUNK > qtMax) return;   // whole block drops out before any barrier
    const int kt0 = c * CHUNK;
    const int kt1 = (qtMax < kt0 + CHUNK - 1) ? qtMax : (kt0 + CHUNK - 1);
    const int w = t >> 6, lane = t & 63, m = lane & 15, g = lane >> 4;
    const int qt_w = 4 * qt4 + (w >> 2);   // this wave's 64-row q-tile
    const int wl = w & 3;                  // wave index within its q-tile

    // Q fragments in registers: row = qt_w*64 + wl*16 + m, d-cols g*8 (+0 / +32)
    const size_t qrow = (size_t)(qt_w * 64 + wl * 16 + m) * DINNER + h * 64;
    const s8v qf_h0 = *(const s8v*)&qhp[qrow + g * 8];
    const s8v qf_h1 = *(const s8v*)&qhp[qrow + 32 + g * 8];
    const s8v qf_l0 = *(const s8v*)&qlp[qrow + g * 8];
    const s8v qf_l1 = *(const s8v*)&qlp[qrow + 32 + g * 8];

    // staging (waves 0-7 only): 512 granules (16B) per 8KB tile, 1 gload per thread/array
    const int sg = w * 64;                 // wave-uniform granule base (w < 8)
    const int srow = (sg + lane) >> 3;
    const int sc = ((lane & 7) ^ (srow & 7)) * 8;   // pre-swizzled source col (elems)
    const bool stager = (w < 8);           // wave-uniform

    f4v o[4] = {{0.f, 0.f, 0.f, 0.f}, {0.f, 0.f, 0.f, 0.f},
                {0.f, 0.f, 0.f, 0.f}, {0.f, 0.f, 0.f, 0.f}};
    float mi_s = -1e30f, li_s = 0.f;   // per-lane stats for q-row wl*16 + m of qt_w

    // prologue: stage first tile into buf 0
    if (stager) {
        const u16* kr = &kh[(size_t)(kt0 * 64) * DINNER + h * 64];
        const u16* lr = &kl[(size_t)(kt0 * 64) * DINNER + h * 64];
        const u16* vr = &vt[(size_t)(h * 64) * SEQ + kt0 * 64];
        gload16(kr + (size_t)srow * DINNER + sc, &KH[0][sg * 8]);
        gload16(lr + (size_t)srow * DINNER + sc, &KL[0][sg * 8]);
        gload16(vr + (size_t)srow * SEQ + sc, &VT[0][sg * 8]);
    }
    __syncthreads();   // drains vmcnt(0)

    int cur = 0;
    for (int kt = kt0; kt <= kt1; ++kt) {
        if (stager && kt < kt1) {   // prefetch next tile into buf^1; drains at mid barrier
            int nb = cur ^ 1;
            const u16* kr = &kh[(size_t)((kt + 1) * 64) * DINNER + h * 64];
            const u16* lr = &kl[(size_t)((kt + 1) * 64) * DINNER + h * 64];
            const u16* vr = &vt[(size_t)(h * 64) * SEQ + (kt + 1) * 64];
            gload16(kr + (size_t)srow * DINNER + sc, &KH[nb][sg * 8]);
            gload16(lr + (size_t)srow * DINNER + sc, &KL[nb][sg * 8]);
            gload16(vr + (size_t)srow * SEQ + sc, &VT[nb][sg * 8]);
        }

        const bool act = (kt <= qt_w);   // wave-uniform; barriers stay outside
        f4v s[4] = {{0.f, 0.f, 0.f, 0.f}, {0.f, 0.f, 0.f, 0.f},
                    {0.f, 0.f, 0.f, 0.f}, {0.f, 0.f, 0.f, 0.f}};
        float alo[4];
        if (act) {
            // S^T: s[ct][r] = S[q = wl*16+m of qt_w][kv = ct*16+g*4+r]
            const char* KHc = (const char*)KH[cur];
            const char* KLc = (const char*)KL[cur];
            __builtin_amdgcn_s_setprio(1);
#pragma unroll
            for (int ct = 0; ct < 4; ++ct) {
                int rr = ct * 16 + m, rb = rr * 128, sw = (rr & 7) << 4;
                s8v bh0 = *(const s8v*)(KHc + rb + ((g * 16) ^ sw));
                s8v bl0 = *(const s8v*)(KLc + rb + ((g * 16) ^ sw));
                s[ct] = MFMA(bh0, qf_h0, s[ct]);
                s[ct] = MFMA(bh0, qf_l0, s[ct]);
                s[ct] = MFMA(bl0, qf_h0, s[ct]);
                s8v bh1 = *(const s8v*)(KHc + rb + ((64 + g * 16) ^ sw));
                s8v bl1 = *(const s8v*)(KLc + rb + ((64 + g * 16) ^ sw));
                s[ct] = MFMA(bh1, qf_h1, s[ct]);
                s[ct] = MFMA(bh1, qf_l1, s[ct]);
                s[ct] = MFMA(bl1, qf_h1, s[ct]);
            }
            __builtin_amdgcn_s_setprio(0);
            if (kt == qt_w) {   // causal: mask kv > q (tile-local)
#pragma unroll
                for (int ct = 0; ct < 4; ++ct)
#pragma unroll
                    for (int r = 0; r < 4; ++r)
                        if (ct * 16 + g * 4 + r > wl * 16 + m) s[ct][r] = -1e30f;
            }

            // lane-local online softmax (16 kv values per lane)
            float rm = -1e30f;
#pragma unroll
            for (int ct = 0; ct < 4; ++ct)
#pragma unroll
                for (int r = 0; r < 4; ++r) rm = fmaxf(rm, s[ct][r]);
            rm = fmaxf(rm, __shfl_xor(rm, 16, 64));
            rm = fmaxf(rm, __shfl_xor(rm, 32, 64));
            float mn = fmaxf(mi_s, rm);
            float al = __expf(mi_s - mn);
            mi_s = mn;
            float rs = 0.f;
#pragma unroll
            for (int ct = 0; ct < 4; ++ct)
#pragma unroll
                for (int r = 0; r < 4; ++r) {
                    s[ct][r] = __expf(s[ct][r] - mn);
                    rs += s[ct][r];
                }
            rs += __shfl_xor(rs, 16, 64);
            rs += __shfl_xor(rs, 32, 64);
            li_s = li_s * al + rs;
#pragma unroll
            for (int r = 0; r < 4; ++r) alo[r] = __shfl(al, g * 4 + r, 64);
        }

        __syncthreads();   // mid: all waves done reading K[cur]; prefetch drains here

        if (act) {
            // P: qtile 0 -> KH[cur], 1 -> KL[cur] (both dead), 2 -> Pex[0], 3 -> Pex[1]
            const int qtl = w >> 2;
            char* Pbuf = (char*)((qtl == 0) ? KH[cur] : (qtl == 1) ? KL[cur]
                                 : (qtl == 2) ? Pex[0] : Pex[1]);
            const int pr = wl * 16 + m, pb = pr * 128, psw = (m & 7) << 4;
#pragma unroll
            for (int ct = 0; ct < 4; ++ct) {
                unsigned w0 = (unsigned)f2bf(s[ct][0]) | ((unsigned)f2bf(s[ct][1]) << 16);
                unsigned w1 = (unsigned)f2bf(s[ct][2]) | ((unsigned)f2bf(s[ct][3]) << 16);
                *(uint2*)(Pbuf + pb + ((ct * 32 + g * 8) ^ psw)) = make_uint2(w0, w1);
            }
#pragma unroll
            for (int ct = 0; ct < 4; ++ct)
#pragma unroll
                for (int r = 0; r < 4; ++r) o[ct][r] *= alo[r];
            // PV: ap from own P rows (wave-private); bv from VT[cur] (swizzled)
            __builtin_amdgcn_s_setprio(1);
#pragma unroll
            for (int kk = 0; kk < 2; ++kk) {
                s8v ap = *(const s8v*)(Pbuf + pb + ((kk * 64 + g * 16) ^ psw));
#pragma unroll
                for (int ct = 0; ct < 4; ++ct) {
                    int vr2 = ct * 16 + m;
                    s8v bv = *(const s8v*)((const char*)VT[cur] + vr2 * 128 +
                                           ((kk * 64 + g * 16) ^ ((vr2 & 7) << 4)));
                    o[ct] = MFMA(ap, bv, o[ct]);
                }
            }
            __builtin_amdgcn_s_setprio(0);
        }

        __syncthreads();   // recycle: buf[cur] reads done before next iter's stage
        cur ^= 1;
    }

    // epilogue: raw partial o (fp32) + per-row (m, l) for this wave's q-tile
    const int T = h * 160 + base16(qt_w) + c;
    float* po = po_sel(T, po_dout, po_wqt);
#pragma unroll
    for (int ct = 0; ct < 4; ++ct)
#pragma unroll
        for (int r = 0; r < 4; ++r)
            po[(size_t)(wl * 16 + g * 4 + r) * 64 + ct * 16 + m] = o[ct][r];
    if (g == 0) {
        ml[(size_t)T * 128 + wl * 16 + m] = mi_s;
        ml[(size_t)T * 128 + 64 + wl * 16 + m] = li_s;
    }
}

// ---------- merge split-KV partials -> atto bf16 ----------
__global__ __launch_bounds__(256) void attn_merge(
    float* __restrict__ po_dout, float* __restrict__ po_wqt,
    const float* __restrict__ ml, u16* __restrict__ atto) {
    const int qt = blockIdx.x, h = blockIdx.y;
    const int nc = (qt >> 4) + 1;
    const int t = threadIdx.x, col = t & 63, rg = t >> 6;
    const int T0 = h * 160 + base16(qt);
    for (int j = 0; j < 16; ++j) {
        int row = rg * 16 + j;
        float mv[4], lv[4], M = -1e30f;
#pragma unroll 4
        for (int cc = 0; cc < 4; ++cc)
            if (cc < nc) {
                mv[cc] = ml[(size_t)(T0 + cc) * 128 + row];
                lv[cc] = ml[(size_t)(T0 + cc) * 128 + 64 + row];
                M = fmaxf(M, mv[cc]);
            }
        float acc = 0.f, den = 0.f;
#pragma unroll 4
        for (int cc = 0; cc < 4; ++cc)
            if (cc < nc) {
                const float* po = po_sel(T0 + cc, po_dout, po_wqt);
                float wg = __expf(mv[cc] - M);
                den += lv[cc] * wg;
                acc += wg * po[(size_t)row * 64 + col];
            }
        atto[(size_t)(qt * 64 + row) * DINNER + h * 64 + col] = f2bf(acc / den);
    }
}

// ---------- fallback: original fused flash attention (used if workspace too small) ----------
__global__ __launch_bounds__(256) void attn_mfma(
    const u16* __restrict__ qh, const u16* __restrict__ ql,
    const u16* __restrict__ kh, const u16* __restrict__ kl,
    const u16* __restrict__ vt, u16* __restrict__ atto) {
    __shared__ u16 Qh[64 * PAD], Ql[64 * PAD], KP[64 * PAD], Kl[64 * PAD], Vt[64 * PAD];
    const int t = threadIdx.x;
    const int qt = blockIdx.x, h = blockIdx.y;
    const int w = t >> 6, lane = t & 63, m = lane & 15, q = lane >> 4;

#pragma unroll
    for (int i = 0; i < 2; ++i) {
        int c = t + i * 256, row = c >> 3, ch = (c & 7) * 8;
        *(uint4*)&Qh[row * PAD + ch] =
            *(const uint4*)&qh[(size_t)(qt * 64 + row) * DINNER + h * 64 + ch];
        *(uint4*)&Ql[row * PAD + ch] =
            *(const uint4*)&ql[(size_t)(qt * 64 + row) * DINNER + h * 64 + ch];
    }

    f4v o[4] = {{0.f, 0.f, 0.f, 0.f}, {0.f, 0.f, 0.f, 0.f},
                {0.f, 0.f, 0.f, 0.f}, {0.f, 0.f, 0.f, 0.f}};
    float mi[4] = {-1e30f, -1e30f, -1e30f, -1e30f};
    float li[4] = {0.f, 0.f, 0.f, 0.f};

    for (int kt = 0; kt <= qt; ++kt) {
        __syncthreads();
#pragma unroll
        for (int i = 0; i < 2; ++i) {
            int c = t + i * 256, row = c >> 3, ch = (c & 7) * 8;
            *(uint4*)&KP[row * PAD + ch] =
                *(const uint4*)&kh[(size_t)(kt * 64 + row) * DINNER + h * 64 + ch];
            *(uint4*)&Kl[row * PAD + ch] =
                *(const uint4*)&kl[(size_t)(kt * 64 + row) * DINNER + h * 64 + ch];
            *(uint4*)&Vt[row * PAD + ch] =
                *(const uint4*)&vt[(size_t)(h * 64 + row) * SEQ + kt * 64 + ch];
        }
        __syncthreads();

        f4v s[4] = {{0.f, 0.f, 0.f, 0.f}, {0.f, 0.f, 0.f, 0.f},
                    {0.f, 0.f, 0.f, 0.f}, {0.f, 0.f, 0.f, 0.f}};
#pragma unroll
        for (int kk = 0; kk < 64; kk += 32) {
            s8v ah = *(const s8v*)&Qh[(w * 16 + m) * PAD + kk + q * 8];
            s8v al = *(const s8v*)&Ql[(w * 16 + m) * PAD + kk + q * 8];
#pragma unroll
            for (int ct = 0; ct < 4; ++ct) {
                s8v bh = *(const s8v*)&KP[(ct * 16 + m) * PAD + kk + q * 8];
                s8v bl = *(const s8v*)&Kl[(ct * 16 + m) * PAD + kk + q * 8];
                s[ct] = MFMA(ah, bh, s[ct]);
                s[ct] = MFMA(al, bh, s[ct]);
                s[ct] = MFMA(ah, bl, s[ct]);
            }
        }
        if (kt == qt) {
#pragma unroll
            for (int ct = 0; ct < 4; ++ct)
#pragma unroll
                for (int r = 0; r < 4; ++r)
                    if (ct * 16 + m > w * 16 + q * 4 + r) s[ct][r] = -1e30f;
        }

        float alpha[4];
#pragma unroll
        for (int r = 0; r < 4; ++r) {
            float rm = fmaxf(fmaxf(s[0][r], s[1][r]), fmaxf(s[2][r], s[3][r]));
#pragma unroll
            for (int off = 8; off >= 1; off >>= 1) rm = fmaxf(rm, __shfl_xor(rm, off, 64));
            float mn = fmaxf(mi[r], rm);
            alpha[r] = __expf(mi[r] - mn);
            mi[r] = mn;
            float rs = 0.f;
#pragma unroll
            for (int ct = 0; ct < 4; ++ct) {
                s[ct][r] = __expf(s[ct][r] - mn);
                rs += s[ct][r];
            }
#pragma unroll
            for (int off = 8; off >= 1; off >>= 1) rs += __shfl_xor(rs, off, 64);
            li[r] = li[r] * alpha[r] + rs;
        }

        __syncthreads();
#pragma unroll
        for (int ct = 0; ct < 4; ++ct)
#pragma unroll
            for (int r = 0; r < 4; ++r) {
                KP[(w * 16 + q * 4 + r) * PAD + ct * 16 + m] = f2bf(s[ct][r]);
                o[ct][r] *= alpha[r];
            }
#pragma unroll
        for (int kk = 0; kk < 64; kk += 32) {
            s8v ap = *(const s8v*)&KP[(w * 16 + m) * PAD + kk + q * 8];
#pragma unroll
            for (int ct = 0; ct < 4; ++ct) {
                s8v bv = *(const s8v*)&Vt[(ct * 16 + m) * PAD + kk + q * 8];
                o[ct] = MFMA(ap, bv, o[ct]);
            }
        }
    }

#pragma unroll
    for (int r = 0; r < 4; ++r) {
        float inv = 1.0f / li[r];
#pragma unroll
        for (int ct = 0; ct < 4; ++ct)
            atto[(size_t)(qt * 64 + w * 16 + q * 4 + r) * DINNER + h * 64 + ct * 16 + m] =
                f2bf(o[ct][r] * inv);
    }
}

// ---------- out projection: 128x128 tile, 512 thr, gload_lds + XOR swizzle ----------
// Grid (8,32) = 256 blocks = exactly 1/CU (perfect balance). 32KB LDS.
__global__ __launch_bounds__(512) void gemm_out_256(const u16* __restrict__ A,
                                                    const u16* __restrict__ Bt,
                                                    float* __restrict__ C) {
    __shared__ __align__(16) u16 As[128 * 64], Bs[128 * 64];
    const int t = threadIdx.x;
    const int bn = blockIdx.x * 128, bm = blockIdx.y * 128;
    const int w = t >> 6, lane = t & 63, m = lane & 15, q = lane >> 4;
    const int wr = w >> 2, wc = w & 3;   // 2(M) x 4(N)
    f4v acc[4][2];
#pragma unroll
    for (int i = 0; i < 4; ++i)
#pragma unroll
        for (int j = 0; j < 2; ++j) acc[i][j] = (f4v){0.f, 0.f, 0.f, 0.f};

    for (int k0 = 0; k0 < DINNER; k0 += 64) {
        __syncthreads();
#pragma unroll
        for (int i = 0; i < 2; ++i) {
            int idx0 = i * 512 + w * 64;
            int row = (idx0 + lane) >> 3;
            int col = ((lane & 7) * 8) ^ ((row & 7) * 8);
            gload16(&A[(size_t)(bm + row) * DINNER + k0 + col], &As[idx0 * 8]);
            gload16(&Bt[(size_t)(bn + row) * DINNER + k0 + col], &Bs[idx0 * 8]);
        }
        __syncthreads();
#pragma unroll
        for (int kk = 0; kk < 64; kk += 32) {
            s8v a_f[4], b_f[2];
#pragma unroll
            for (int f = 0; f < 4; ++f) {
                int ar = wr * 64 + f * 16 + m;
                a_f[f] = *(const s8v*)((const char*)As + ar * 128 +
                                       (((kk + q * 8) * 2) ^ ((ar & 7) << 4)));
            }
#pragma unroll
            for (int f = 0; f < 2; ++f) {
                int br = wc * 32 + f * 16 + m;
                b_f[f] = *(const s8v*)((const char*)Bs + br * 128 +
                                       (((kk + q * 8) * 2) ^ ((br & 7) << 4)));
            }
#pragma unroll
            for (int fm = 0; fm < 4; ++fm)
#pragma unroll
                for (int fn = 0; fn < 2; ++fn)
                    acc[fm][fn] = MFMA(a_f[fm], b_f[fn], acc[fm][fn]);
        }
    }
#pragma unroll
    for (int fm = 0; fm < 4; ++fm)
#pragma unroll
        for (int fn = 0; fn < 2; ++fn)
#pragma unroll
            for (int r = 0; r < 4; ++r)
                C[(size_t)(bm + wr * 64 + fm * 16 + q * 4 + r) * DIM +
                  bn + wc * 32 + fn * 16 + m] = acc[fm][fn][r];
}

extern "C" void kernel_launch(void* const* d_in, const int* in_sizes, int n_in,
                              void* d_out, int out_size, void* d_ws, size_t ws_size,
                              hipStream_t stream) {
    const float* x     = (const float*)d_in[0];
    const float* gamma = (const float*)d_in[1];
    const float* w_qkv = (const float*)d_in[2];
    const float* w_out = (const float*)d_in[3];
    float* out = (float*)d_out;

    // normed hi/lo live in d_out (exact fit; consumed by gemm_qkv before partials overwrite)
    u16* nh = (u16*)d_out;
    u16* nl = nh + (size_t)SEQ * DIM;

    u16* p = (u16*)d_ws;
    u16* wqt_h = p; p += (size_t)QKVW * DIM;
    u16* wqt_l = p; p += (size_t)QKVW * DIM;
    u16* wot   = p; p += (size_t)DIM * DINNER;
    u16* qh = p; p += (size_t)SEQ * DINNER;
    u16* ql = p; p += (size_t)SEQ * DINNER;
    u16* kh = p; p += (size_t)SEQ * DINNER;
    u16* kl = p; p += (size_t)SEQ * DINNER;
    u16* vt = p; p += (size_t)DINNER * SEQ;
    u16* atto = p; p += (size_t)SEQ * DINNER;

    // split-KV partials: 1280 chunk-tiles x 16KB fp32. Tiles 0..1023 in d_out (16.78MB),
    // 1024..1279 in the dead wqt_h/wqt_l region. ml in ws.
    float* po_dout = (float*)d_out;
    float* po_wqt  = (float*)wqt_h;
    float* ml      = (float*)p;
    const size_t need = (size_t)((char*)(ml + (size_t)1280 * 128) - (char*)d_ws);  // ~32 MB
    const bool split = ws_size >= need;

    transpose_split<<<dim3(QKVW / 64, DIM / 64), 256, 0, stream>>>(w_qkv, wqt_h, wqt_l,
                                                                   DIM, QKVW, 1);
    transpose_split<<<dim3(DIM / 64, DINNER / 64), 256, 0, stream>>>(w_out, wot, nullptr,
                                                                     DINNER, DIM, 0);
    rmsnorm_split<<<SEQ, 256, 0, stream>>>(x, gamma, nh, nl);
    gemm_qkv_64x128<<<dim3(QKVW / 128, SEQ / 64), 256, 0, stream>>>(nh, nl, wqt_h, wqt_l,
                                                                    qh, ql, kh, kl, vt);
    if (split) {
        attn_chunk<<<dim3(64, HEADS), 1024, 0, stream>>>(qh, ql, kh, kl, vt,
                                                         po_dout, po_wqt, ml);
        attn_merge<<<dim3(SEQ / 64, HEADS), 256, 0, stream>>>(po_dout, po_wqt, ml, atto);
    } else {
        attn_mfma<<<dim3(SEQ / 64, HEADS), 256, 0, stream>>>(qh, ql, kh, kl, vt, atto);
    }
    gemm_out_256<<<dim3(DIM / 128, SEQ / 128), 512, 0, stream>>>(atto, wot, out);
}

// Round 16
// 264.665 us; speedup vs baseline: 1.0436x; 1.0436x over previous
//
#include <hip/hip_runtime.h>
#include <math.h>

#define SEQ 4096
#define DIM 1024
#define HEADS 8
#define DINNER 512
#define QKVW 1536
#define PAD 80   // LDS row stride (bf16 elems) for legacy fallback kernels
#define CHUNK 16 // K-tiles (of 64) per split-KV chunk

typedef unsigned short u16;
typedef __attribute__((ext_vector_type(8))) short s8v;   // 8 bf16 (4 VGPRs)
typedef __attribute__((ext_vector_type(4))) float f4v;   // 4 fp32 acc
#define MFMA(a, b, c) __builtin_amdgcn_mfma_f32_16x16x32_bf16(a, b, c, 0, 0, 0)

__device__ __forceinline__ u16 f2bf(float f) {
    unsigned u = __float_as_uint(f);
    u += 0x7fff + ((u >> 16) & 1);   // RNE
    return (u16)(u >> 16);
}
__device__ __forceinline__ float bf2f(u16 b) { return __uint_as_float(((unsigned)b) << 16); }

// async global->LDS, 16B per lane. LDS dest is wave-uniform base + lane*16 (HW rule);
// the GLOBAL source is per-lane and pre-swizzled to realize the LDS XOR swizzle (rule #21).
__device__ __forceinline__ void gload16(const u16* g, u16* l) {
    __builtin_amdgcn_global_load_lds(
        (const __attribute__((address_space(1))) unsigned int*)g,
        (__attribute__((address_space(3))) unsigned int*)l, 16, 0, 0);
}

// chunk-tile flat index: T = h*160 + base16(qt) + c; nc(qt) = qt/16 + 1
__device__ __forceinline__ int base16(int qt) {
    int a = qt >> 4, b = qt & 15;
    return 8 * a * (a + 1) + b * (a + 1);
}
// partials: tiles 0..1023 in d_out, 1024..1279 in the dead wqt region
__device__ __forceinline__ float* po_sel(int T, float* pd, float* pw) {
    return (T < 1024) ? pd + (size_t)T * 4096 : pw + (size_t)(T - 1024) * 4096;
}

// ---------- RMSNorm -> split bf16 (hi, lo), vectorized (G13) ----------
__global__ __launch_bounds__(256) void rmsnorm_split(const float* __restrict__ x,
                                                     const float* __restrict__ gamma,
                                                     u16* __restrict__ hi,
                                                     u16* __restrict__ lo) {
    __shared__ float red[4];
    const int row = blockIdx.x, t = threadIdx.x;
    const float4 xv = ((const float4*)(x + (size_t)row * DIM))[t];
    float ss = xv.x * xv.x + xv.y * xv.y + xv.z * xv.z + xv.w * xv.w;
#pragma unroll
    for (int off = 32; off >= 1; off >>= 1) ss += __shfl_xor(ss, off, 64);
    if ((t & 63) == 0) red[t >> 6] = ss;
    __syncthreads();
    float scale = 32.0f / fmaxf(sqrtf(red[0] + red[1] + red[2] + red[3]), 1e-12f);
    const float4 gv = ((const float4*)gamma)[t];
    float y[4] = {xv.x * scale * gv.x, xv.y * scale * gv.y,
                  xv.z * scale * gv.z, xv.w * scale * gv.w};
    unsigned hw0, hw1, lw0, lw1;
    {
        u16 h0 = f2bf(y[0]), h1 = f2bf(y[1]), h2 = f2bf(y[2]), h3 = f2bf(y[3]);
        hw0 = (unsigned)h0 | ((unsigned)h1 << 16);
        hw1 = (unsigned)h2 | ((unsigned)h3 << 16);
        lw0 = (unsigned)f2bf(y[0] - bf2f(h0)) | ((unsigned)f2bf(y[1] - bf2f(h1)) << 16);
        lw1 = (unsigned)f2bf(y[2] - bf2f(h2)) | ((unsigned)f2bf(y[3] - bf2f(h3)) << 16);
    }
    *(uint2*)&hi[(size_t)row * DIM + t * 4] = make_uint2(hw0, hw1);
    *(uint2*)&lo[(size_t)row * DIM + t * 4] = make_uint2(lw0, lw1);
}

// ---------- transpose fp32 [R][C] -> bf16 hi/lo [C][R] ----------
__global__ __launch_bounds__(256) void transpose_split(const float* __restrict__ in,
                                                       u16* __restrict__ hi,
                                                       u16* __restrict__ lo,
                                                       int R, int C, int want_lo) {
    __shared__ float tile[64][65];
    const int c0 = blockIdx.x * 64, r0 = blockIdx.y * 64;
    const int t = threadIdx.x, col = t & 63, rb = t >> 6;
#pragma unroll
    for (int j = 0; j < 16; ++j)
        tile[rb + j * 4][col] = in[(size_t)(r0 + rb + j * 4) * C + c0 + col];
    __syncthreads();
#pragma unroll
    for (int j = 0; j < 16; ++j) {
        int cc = rb + j * 4;
        float v = tile[col][cc];
        size_t oi = (size_t)(c0 + cc) * R + r0 + col;
        u16 h = f2bf(v);
        hi[oi] = h;
        if (want_lo) lo[oi] = f2bf(v - bf2f(h));
    }
}

// ---------- QKV GEMM: 128x96 tile, 512 blocks = EXACTLY 2/CU, gload_lds + XOR swizzle ----------
// Balance AND efficiency: grid (16,32)=512 blocks = 2/CU (no R14 1.5/CU makespan waste);
// staging 4.67 B/output/K-step (vs 4.0 for 128x128, 6.0 for the failed 64x128). 256 thr,
// 4 waves in 2(M)x2(N), each 64x48 (acc[4][3]). LDS 56KB -> 2 blocks/CU (matches grid).
// Region (q/k/v) computed PER ELEMENT in epilogue: bn is a multiple of 96, so boundary
// blocks straddle 512/1024 (divergence in 2 of 16 N-blocks, epilogue-only).
__global__ __launch_bounds__(256) void gemm_qkv_96(
    const u16* __restrict__ Ah, const u16* __restrict__ Al,
    const u16* __restrict__ Bh, const u16* __restrict__ Bl,
    u16* __restrict__ qh, u16* __restrict__ ql,
    u16* __restrict__ kh, u16* __restrict__ kl, u16* __restrict__ vtp) {
    __shared__ __align__(16) u16 AsH[128 * 64], AsL[128 * 64];
    __shared__ __align__(16) u16 BsH[96 * 64], BsL[96 * 64];
    const int t = threadIdx.x;
    const int bn = blockIdx.x * 96, bm = blockIdx.y * 128;
    const int w = t >> 6, lane = t & 63, m = lane & 15, q = lane >> 4;
    const int wr = w >> 1, wc = w & 1;   // 2(M) x 2(N) wave grid; wave = 64 x 48
    f4v acc[4][3];
#pragma unroll
    for (int i = 0; i < 4; ++i)
#pragma unroll
        for (int j = 0; j < 3; ++j) acc[i][j] = (f4v){0.f, 0.f, 0.f, 0.f};

    for (int k0 = 0; k0 < DIM; k0 += 64) {
        __syncthreads();
        // A: 128x64 = 1024 granules (4 passes); B: 96x64 = 768 granules (3 passes)
#pragma unroll
        for (int i = 0; i < 4; ++i) {
            int idx0 = i * 256 + w * 64;              // wave-uniform LDS granule base
            int row = (idx0 + lane) >> 3;
            int col = ((lane & 7) * 8) ^ ((row & 7) * 8);   // pre-swizzled source column
            gload16(&Ah[(size_t)(bm + row) * DIM + k0 + col], &AsH[idx0 * 8]);
            gload16(&Al[(size_t)(bm + row) * DIM + k0 + col], &AsL[idx0 * 8]);
            if (i < 3) {
                gload16(&Bh[(size_t)(bn + row) * DIM + k0 + col], &BsH[idx0 * 8]);
                gload16(&Bl[(size_t)(bn + row) * DIM + k0 + col], &BsL[idx0 * 8]);
            }
        }
        __syncthreads();   // compiler drains vmcnt(0) here
#pragma unroll
        for (int kk = 0; kk < 64; kk += 32) {
            s8v a_h[4], a_l[4], b_h[3], b_l[3];
#pragma unroll
            for (int f = 0; f < 4; ++f) {
                int ar = wr * 64 + f * 16 + m;
                int ab = ar * 128 + (((kk + q * 8) * 2) ^ ((ar & 7) << 4));
                a_h[f] = *(const s8v*)((const char*)AsH + ab);
                a_l[f] = *(const s8v*)((const char*)AsL + ab);
            }
#pragma unroll
            for (int f = 0; f < 3; ++f) {
                int br = wc * 48 + f * 16 + m;
                int bb = br * 128 + (((kk + q * 8) * 2) ^ ((br & 7) << 4));
                b_h[f] = *(const s8v*)((const char*)BsH + bb);
                b_l[f] = *(const s8v*)((const char*)BsL + bb);
            }
#pragma unroll
            for (int fm = 0; fm < 4; ++fm)
#pragma unroll
                for (int fn = 0; fn < 3; ++fn) {
                    acc[fm][fn] = MFMA(a_h[fm], b_h[fn], acc[fm][fn]);
                    acc[fm][fn] = MFMA(a_l[fm], b_h[fn], acc[fm][fn]);
                    acc[fm][fn] = MFMA(a_h[fm], b_l[fn], acc[fm][fn]);
                }
        }
    }
#pragma unroll
    for (int fm = 0; fm < 4; ++fm)
#pragma unroll
        for (int fn = 0; fn < 3; ++fn)
#pragma unroll
            for (int r = 0; r < 4; ++r) {
                int gr = bm + wr * 64 + fm * 16 + q * 4 + r;
                int gc = bn + wc * 48 + fn * 16 + m;
                float v = acc[fm][fn][r];
                int region = gc >> 9;   // per-element (boundary blocks straddle 512/1024)
                if (region == 0) {
                    v *= 8.0f;   // q * sqrt(d), faithful to reference
                    u16 h = f2bf(v);
                    qh[(size_t)gr * DINNER + gc] = h;
                    ql[(size_t)gr * DINNER + gc] = f2bf(v - bf2f(h));
                } else if (region == 1) {
                    u16 h = f2bf(v);
                    kh[(size_t)gr * DINNER + (gc - 512)] = h;
                    kl[(size_t)gr * DINNER + (gc - 512)] = f2bf(v - bf2f(h));
                } else {
                    vtp[(size_t)(gc - 1024) * SEQ + gr] = f2bf(v);
                }
            }
}

// ---------- split-KV flash attention: 16 WAVES SHARE ONE STAGED K/V TILE (R13) ----------
__global__ __launch_bounds__(1024) void attn_chunk(
    const u16* __restrict__ qhp, const u16* __restrict__ qlp,
    const u16* __restrict__ kh, const u16* __restrict__ kl,
    const u16* __restrict__ vt,
    float* __restrict__ po_dout, float* __restrict__ po_wqt,
    float* __restrict__ ml) {
    __shared__ __align__(16) u16 KH[2][64 * 64], KL[2][64 * 64], VT[2][64 * 64];
    __shared__ __align__(16) u16 Pex[2][64 * 64];
    const int t = threadIdx.x;
    const int bx = blockIdx.x;
    const int qt4 = 15 - (bx >> 2), c = bx & 3, h = blockIdx.y;
    const int qtMax = 4 * qt4 + 3;
    if (c * CHUNK > qtMax) return;   // whole block drops out before any barrier
    const int kt0 = c * CHUNK;
    const int kt1 = (qtMax < kt0 + CHUNK - 1) ? qtMax : (kt0 + CHUNK - 1);
    const int w = t >> 6, lane = t & 63, m = lane & 15, g = lane >> 4;
    const int qt_w = 4 * qt4 + (w >> 2);   // this wave's 64-row q-tile
    const int wl = w & 3;                  // wave index within its q-tile

    // Q fragments in registers: row = qt_w*64 + wl*16 + m, d-cols g*8 (+0 / +32)
    const size_t qrow = (size_t)(qt_w * 64 + wl * 16 + m) * DINNER + h * 64;
    const s8v qf_h0 = *(const s8v*)&qhp[qrow + g * 8];
    const s8v qf_h1 = *(const s8v*)&qhp[qrow + 32 + g * 8];
    const s8v qf_l0 = *(const s8v*)&qlp[qrow + g * 8];
    const s8v qf_l1 = *(const s8v*)&qlp[qrow + 32 + g * 8];

    // staging (waves 0-7 only): 512 granules (16B) per 8KB tile, 1 gload per thread/array
    const int sg = w * 64;                 // wave-uniform granule base (w < 8)
    const int srow = (sg + lane) >> 3;
    const int sc = ((lane & 7) ^ (srow & 7)) * 8;   // pre-swizzled source col (elems)
    const bool stager = (w < 8);           // wave-uniform

    f4v o[4] = {{0.f, 0.f, 0.f, 0.f}, {0.f, 0.f, 0.f, 0.f},
                {0.f, 0.f, 0.f, 0.f}, {0.f, 0.f, 0.f, 0.f}};
    float mi_s = -1e30f, li_s = 0.f;   // per-lane stats for q-row wl*16 + m of qt_w

    // prologue: stage first tile into buf 0
    if (stager) {
        const u16* kr = &kh[(size_t)(kt0 * 64) * DINNER + h * 64];
        const u16* lr = &kl[(size_t)(kt0 * 64) * DINNER + h * 64];
        const u16* vr = &vt[(size_t)(h * 64) * SEQ + kt0 * 64];
        gload16(kr + (size_t)srow * DINNER + sc, &KH[0][sg * 8]);
        gload16(lr + (size_t)srow * DINNER + sc, &KL[0][sg * 8]);
        gload16(vr + (size_t)srow * SEQ + sc, &VT[0][sg * 8]);
    }
    __syncthreads();   // drains vmcnt(0)

    int cur = 0;
    for (int kt = kt0; kt <= kt1; ++kt) {
        if (stager && kt < kt1) {   // prefetch next tile into buf^1; drains at mid barrier
            int nb = cur ^ 1;
            const u16* kr = &kh[(size_t)((kt + 1) * 64) * DINNER + h * 64];
            const u16* lr = &kl[(size_t)((kt + 1) * 64) * DINNER + h * 64];
            const u16* vr = &vt[(size_t)(h * 64) * SEQ + (kt + 1) * 64];
            gload16(kr + (size_t)srow * DINNER + sc, &KH[nb][sg * 8]);
            gload16(lr + (size_t)srow * DINNER + sc, &KL[nb][sg * 8]);
            gload16(vr + (size_t)srow * SEQ + sc, &VT[nb][sg * 8]);
        }

        const bool act = (kt <= qt_w);   // wave-uniform; barriers stay outside
        f4v s[4] = {{0.f, 0.f, 0.f, 0.f}, {0.f, 0.f, 0.f, 0.f},
                    {0.f, 0.f, 0.f, 0.f}, {0.f, 0.f, 0.f, 0.f}};
        float alo[4];
        if (act) {
            // S^T: s[ct][r] = S[q = wl*16+m of qt_w][kv = ct*16+g*4+r]
            const char* KHc = (const char*)KH[cur];
            const char* KLc = (const char*)KL[cur];
            __builtin_amdgcn_s_setprio(1);
#pragma unroll
            for (int ct = 0; ct < 4; ++ct) {
                int rr = ct * 16 + m, rb = rr * 128, sw = (rr & 7) << 4;
                s8v bh0 = *(const s8v*)(KHc + rb + ((g * 16) ^ sw));
                s8v bl0 = *(const s8v*)(KLc + rb + ((g * 16) ^ sw));
                s[ct] = MFMA(bh0, qf_h0, s[ct]);
                s[ct] = MFMA(bh0, qf_l0, s[ct]);
                s[ct] = MFMA(bl0, qf_h0, s[ct]);
                s8v bh1 = *(const s8v*)(KHc + rb + ((64 + g * 16) ^ sw));
                s8v bl1 = *(const s8v*)(KLc + rb + ((64 + g * 16) ^ sw));
                s[ct] = MFMA(bh1, qf_h1, s[ct]);
                s[ct] = MFMA(bh1, qf_l1, s[ct]);
                s[ct] = MFMA(bl1, qf_h1, s[ct]);
            }
            __builtin_amdgcn_s_setprio(0);
            if (kt == qt_w) {   // causal: mask kv > q (tile-local)
#pragma unroll
                for (int ct = 0; ct < 4; ++ct)
#pragma unroll
                    for (int r = 0; r < 4; ++r)
                        if (ct * 16 + g * 4 + r > wl * 16 + m) s[ct][r] = -1e30f;
            }

            // lane-local online softmax (16 kv values per lane)
            float rm = -1e30f;
#pragma unroll
            for (int ct = 0; ct < 4; ++ct)
#pragma unroll
                for (int r = 0; r < 4; ++r) rm = fmaxf(rm, s[ct][r]);
            rm = fmaxf(rm, __shfl_xor(rm, 16, 64));
            rm = fmaxf(rm, __shfl_xor(rm, 32, 64));
            float mn = fmaxf(mi_s, rm);
            float al = __expf(mi_s - mn);
            mi_s = mn;
            float rs = 0.f;
#pragma unroll
            for (int ct = 0; ct < 4; ++ct)
#pragma unroll
                for (int r = 0; r < 4; ++r) {
                    s[ct][r] = __expf(s[ct][r] - mn);
                    rs += s[ct][r];
                }
            rs += __shfl_xor(rs, 16, 64);
            rs += __shfl_xor(rs, 32, 64);
            li_s = li_s * al + rs;
#pragma unroll
            for (int r = 0; r < 4; ++r) alo[r] = __shfl(al, g * 4 + r, 64);
        }

        __syncthreads();   // mid: all waves done reading K[cur]; prefetch drains here

        if (act) {
            // P: qtile 0 -> KH[cur], 1 -> KL[cur] (both dead), 2 -> Pex[0], 3 -> Pex[1]
            const int qtl = w >> 2;
            char* Pbuf = (char*)((qtl == 0) ? KH[cur] : (qtl == 1) ? KL[cur]
                                 : (qtl == 2) ? Pex[0] : Pex[1]);
            const int pr = wl * 16 + m, pb = pr * 128, psw = (m & 7) << 4;
#pragma unroll
            for (int ct = 0; ct < 4; ++ct) {
                unsigned w0 = (unsigned)f2bf(s[ct][0]) | ((unsigned)f2bf(s[ct][1]) << 16);
                unsigned w1 = (unsigned)f2bf(s[ct][2]) | ((unsigned)f2bf(s[ct][3]) << 16);
                *(uint2*)(Pbuf + pb + ((ct * 32 + g * 8) ^ psw)) = make_uint2(w0, w1);
            }
#pragma unroll
            for (int ct = 0; ct < 4; ++ct)
#pragma unroll
                for (int r = 0; r < 4; ++r) o[ct][r] *= alo[r];
            // PV: ap from own P rows (wave-private); bv from VT[cur] (swizzled)
            __builtin_amdgcn_s_setprio(1);
#pragma unroll
            for (int kk = 0; kk < 2; ++kk) {
                s8v ap = *(const s8v*)(Pbuf + pb + ((kk * 64 + g * 16) ^ psw));
#pragma unroll
                for (int ct = 0; ct < 4; ++ct) {
                    int vr2 = ct * 16 + m;
                    s8v bv = *(const s8v*)((const char*)VT[cur] + vr2 * 128 +
                                           ((kk * 64 + g * 16) ^ ((vr2 & 7) << 4)));
                    o[ct] = MFMA(ap, bv, o[ct]);
                }
            }
            __builtin_amdgcn_s_setprio(0);
        }

        __syncthreads();   // recycle: buf[cur] reads done before next iter's stage
        cur ^= 1;
    }

    // epilogue: raw partial o (fp32) + per-row (m, l) for this wave's q-tile
    const int T = h * 160 + base16(qt_w) + c;
    float* po = po_sel(T, po_dout, po_wqt);
#pragma unroll
    for (int ct = 0; ct < 4; ++ct)
#pragma unroll
        for (int r = 0; r < 4; ++r)
            po[(size_t)(wl * 16 + g * 4 + r) * 64 + ct * 16 + m] = o[ct][r];
    if (g == 0) {
        ml[(size_t)T * 128 + wl * 16 + m] = mi_s;
        ml[(size_t)T * 128 + 64 + wl * 16 + m] = li_s;
    }
}

// ---------- merge split-KV partials -> atto bf16 ----------
__global__ __launch_bounds__(256) void attn_merge(
    float* __restrict__ po_dout, float* __restrict__ po_wqt,
    const float* __restrict__ ml, u16* __restrict__ atto) {
    const int qt = blockIdx.x, h = blockIdx.y;
    const int nc = (qt >> 4) + 1;
    const int t = threadIdx.x, col = t & 63, rg = t >> 6;
    const int T0 = h * 160 + base16(qt);
    for (int j = 0; j < 16; ++j) {
        int row = rg * 16 + j;
        float mv[4], lv[4], M = -1e30f;
#pragma unroll 4
        for (int cc = 0; cc < 4; ++cc)
            if (cc < nc) {
                mv[cc] = ml[(size_t)(T0 + cc) * 128 + row];
                lv[cc] = ml[(size_t)(T0 + cc) * 128 + 64 + row];
                M = fmaxf(M, mv[cc]);
            }
        float acc = 0.f, den = 0.f;
#pragma unroll 4
        for (int cc = 0; cc < 4; ++cc)
            if (cc < nc) {
                const float* po = po_sel(T0 + cc, po_dout, po_wqt);
                float wg = __expf(mv[cc] - M);
                den += lv[cc] * wg;
                acc += wg * po[(size_t)row * 64 + col];
            }
        atto[(size_t)(qt * 64 + row) * DINNER + h * 64 + col] = f2bf(acc / den);
    }
}

// ---------- fallback: original fused flash attention (used if workspace too small) ----------
__global__ __launch_bounds__(256) void attn_mfma(
    const u16* __restrict__ qh, const u16* __restrict__ ql,
    const u16* __restrict__ kh, const u16* __restrict__ kl,
    const u16* __restrict__ vt, u16* __restrict__ atto) {
    __shared__ u16 Qh[64 * PAD], Ql[64 * PAD], KP[64 * PAD], Kl[64 * PAD], Vt[64 * PAD];
    const int t = threadIdx.x;
    const int qt = blockIdx.x, h = blockIdx.y;
    const int w = t >> 6, lane = t & 63, m = lane & 15, q = lane >> 4;

#pragma unroll
    for (int i = 0; i < 2; ++i) {
        int c = t + i * 256, row = c >> 3, ch = (c & 7) * 8;
        *(uint4*)&Qh[row * PAD + ch] =
            *(const uint4*)&qh[(size_t)(qt * 64 + row) * DINNER + h * 64 + ch];
        *(uint4*)&Ql[row * PAD + ch] =
            *(const uint4*)&ql[(size_t)(qt * 64 + row) * DINNER + h * 64 + ch];
    }

    f4v o[4] = {{0.f, 0.f, 0.f, 0.f}, {0.f, 0.f, 0.f, 0.f},
                {0.f, 0.f, 0.f, 0.f}, {0.f, 0.f, 0.f, 0.f}};
    float mi[4] = {-1e30f, -1e30f, -1e30f, -1e30f};
    float li[4] = {0.f, 0.f, 0.f, 0.f};

    for (int kt = 0; kt <= qt; ++kt) {
        __syncthreads();
#pragma unroll
        for (int i = 0; i < 2; ++i) {
            int c = t + i * 256, row = c >> 3, ch = (c & 7) * 8;
            *(uint4*)&KP[row * PAD + ch] =
                *(const uint4*)&kh[(size_t)(kt * 64 + row) * DINNER + h * 64 + ch];
            *(uint4*)&Kl[row * PAD + ch] =
                *(const uint4*)&kl[(size_t)(kt * 64 + row) * DINNER + h * 64 + ch];
            *(uint4*)&Vt[row * PAD + ch] =
                *(const uint4*)&vt[(size_t)(h * 64 + row) * SEQ + kt * 64 + ch];
        }
        __syncthreads();

        f4v s[4] = {{0.f, 0.f, 0.f, 0.f}, {0.f, 0.f, 0.f, 0.f},
                    {0.f, 0.f, 0.f, 0.f}, {0.f, 0.f, 0.f, 0.f}};
#pragma unroll
        for (int kk = 0; kk < 64; kk += 32) {
            s8v ah = *(const s8v*)&Qh[(w * 16 + m) * PAD + kk + q * 8];
            s8v al = *(const s8v*)&Ql[(w * 16 + m) * PAD + kk + q * 8];
#pragma unroll
            for (int ct = 0; ct < 4; ++ct) {
                s8v bh = *(const s8v*)&KP[(ct * 16 + m) * PAD + kk + q * 8];
                s8v bl = *(const s8v*)&Kl[(ct * 16 + m) * PAD + kk + q * 8];
                s[ct] = MFMA(ah, bh, s[ct]);
                s[ct] = MFMA(al, bh, s[ct]);
                s[ct] = MFMA(ah, bl, s[ct]);
            }
        }
        if (kt == qt) {
#pragma unroll
            for (int ct = 0; ct < 4; ++ct)
#pragma unroll
                for (int r = 0; r < 4; ++r)
                    if (ct * 16 + m > w * 16 + q * 4 + r) s[ct][r] = -1e30f;
        }

        float alpha[4];
#pragma unroll
        for (int r = 0; r < 4; ++r) {
            float rm = fmaxf(fmaxf(s[0][r], s[1][r]), fmaxf(s[2][r], s[3][r]));
#pragma unroll
            for (int off = 8; off >= 1; off >>= 1) rm = fmaxf(rm, __shfl_xor(rm, off, 64));
            float mn = fmaxf(mi[r], rm);
            alpha[r] = __expf(mi[r] - mn);
            mi[r] = mn;
            float rs = 0.f;
#pragma unroll
            for (int ct = 0; ct < 4; ++ct) {
                s[ct][r] = __expf(s[ct][r] - mn);
                rs += s[ct][r];
            }
#pragma unroll
            for (int off = 8; off >= 1; off >>= 1) rs += __shfl_xor(rs, off, 64);
            li[r] = li[r] * alpha[r] + rs;
        }

        __syncthreads();
#pragma unroll
        for (int ct = 0; ct < 4; ++ct)
#pragma unroll
            for (int r = 0; r < 4; ++r) {
                KP[(w * 16 + q * 4 + r) * PAD + ct * 16 + m] = f2bf(s[ct][r]);
                o[ct][r] *= alpha[r];
            }
#pragma unroll
        for (int kk = 0; kk < 64; kk += 32) {
            s8v ap = *(const s8v*)&KP[(w * 16 + m) * PAD + kk + q * 8];
#pragma unroll
            for (int ct = 0; ct < 4; ++ct) {
                s8v bv = *(const s8v*)&Vt[(ct * 16 + m) * PAD + kk + q * 8];
                o[ct] = MFMA(ap, bv, o[ct]);
            }
        }
    }

#pragma unroll
    for (int r = 0; r < 4; ++r) {
        float inv = 1.0f / li[r];
#pragma unroll
        for (int ct = 0; ct < 4; ++ct)
            atto[(size_t)(qt * 64 + w * 16 + q * 4 + r) * DINNER + h * 64 + ct * 16 + m] =
                f2bf(o[ct][r] * inv);
    }
}

// ---------- out projection: 128x128 tile, 512 thr, gload_lds + XOR swizzle ----------
// Grid (8,32) = 256 blocks = exactly 1/CU (perfect balance). 32KB LDS.
__global__ __launch_bounds__(512) void gemm_out_256(const u16* __restrict__ A,
                                                    const u16* __restrict__ Bt,
                                                    float* __restrict__ C) {
    __shared__ __align__(16) u16 As[128 * 64], Bs[128 * 64];
    const int t = threadIdx.x;
    const int bn = blockIdx.x * 128, bm = blockIdx.y * 128;
    const int w = t >> 6, lane = t & 63, m = lane & 15, q = lane >> 4;
    const int wr = w >> 2, wc = w & 3;   // 2(M) x 4(N)
    f4v acc[4][2];
#pragma unroll
    for (int i = 0; i < 4; ++i)
#pragma unroll
        for (int j = 0; j < 2; ++j) acc[i][j] = (f4v){0.f, 0.f, 0.f, 0.f};

    for (int k0 = 0; k0 < DINNER; k0 += 64) {
        __syncthreads();
#pragma unroll
        for (int i = 0; i < 2; ++i) {
            int idx0 = i * 512 + w * 64;
            int row = (idx0 + lane) >> 3;
            int col = ((lane & 7) * 8) ^ ((row & 7) * 8);
            gload16(&A[(size_t)(bm + row) * DINNER + k0 + col], &As[idx0 * 8]);
            gload16(&Bt[(size_t)(bn + row) * DINNER + k0 + col], &Bs[idx0 * 8]);
        }
        __syncthreads();
#pragma unroll
        for (int kk = 0; kk < 64; kk += 32) {
            s8v a_f[4], b_f[2];
#pragma unroll
            for (int f = 0; f < 4; ++f) {
                int ar = wr * 64 + f * 16 + m;
                a_f[f] = *(const s8v*)((const char*)As + ar * 128 +
                                       (((kk + q * 8) * 2) ^ ((ar & 7) << 4)));
            }
#pragma unroll
            for (int f = 0; f < 2; ++f) {
                int br = wc * 32 + f * 16 + m;
                b_f[f] = *(const s8v*)((const char*)Bs + br * 128 +
                                       (((kk + q * 8) * 2) ^ ((br & 7) << 4)));
            }
#pragma unroll
            for (int fm = 0; fm < 4; ++fm)
#pragma unroll
                for (int fn = 0; fn < 2; ++fn)
                    acc[fm][fn] = MFMA(a_f[fm], b_f[fn], acc[fm][fn]);
        }
    }
#pragma unroll
    for (int fm = 0; fm < 4; ++fm)
#pragma unroll
        for (int fn = 0; fn < 2; ++fn)
#pragma unroll
            for (int r = 0; r < 4; ++r)
                C[(size_t)(bm + wr * 64 + fm * 16 + q * 4 + r) * DIM +
                  bn + wc * 32 + fn * 16 + m] = acc[fm][fn][r];
}

extern "C" void kernel_launch(void* const* d_in, const int* in_sizes, int n_in,
                              void* d_out, int out_size, void* d_ws, size_t ws_size,
                              hipStream_t stream) {
    const float* x     = (const float*)d_in[0];
    const float* gamma = (const float*)d_in[1];
    const float* w_qkv = (const float*)d_in[2];
    const float* w_out = (const float*)d_in[3];
    float* out = (float*)d_out;

    // normed hi/lo live in d_out (exact fit; consumed by gemm_qkv before partials overwrite)
    u16* nh = (u16*)d_out;
    u16* nl = nh + (size_t)SEQ * DIM;

    u16* p = (u16*)d_ws;
    u16* wqt_h = p; p += (size_t)QKVW * DIM;
    u16* wqt_l = p; p += (size_t)QKVW * DIM;
    u16* wot   = p; p += (size_t)DIM * DINNER;
    u16* qh = p; p += (size_t)SEQ * DINNER;
    u16* ql = p; p += (size_t)SEQ * DINNER;
    u16* kh = p; p += (size_t)SEQ * DINNER;
    u16* kl = p; p += (size_t)SEQ * DINNER;
    u16* vt = p; p += (size_t)DINNER * SEQ;
    u16* atto = p; p += (size_t)SEQ * DINNER;

    // split-KV partials: 1280 chunk-tiles x 16KB fp32. Tiles 0..1023 in d_out (16.78MB),
    // 1024..1279 in the dead wqt_h/wqt_l region. ml in ws.
    float* po_dout = (float*)d_out;
    float* po_wqt  = (float*)wqt_h;
    float* ml      = (float*)p;
    const size_t need = (size_t)((char*)(ml + (size_t)1280 * 128) - (char*)d_ws);  // ~32 MB
    const bool split = ws_size >= need;

    transpose_split<<<dim3(QKVW / 64, DIM / 64), 256, 0, stream>>>(w_qkv, wqt_h, wqt_l,
                                                                   DIM, QKVW, 1);
    transpose_split<<<dim3(DIM / 64, DINNER / 64), 256, 0, stream>>>(w_out, wot, nullptr,
                                                                     DINNER, DIM, 0);
    rmsnorm_split<<<SEQ, 256, 0, stream>>>(x, gamma, nh, nl);
    gemm_qkv_96<<<dim3(QKVW / 96, SEQ / 128), 256, 0, stream>>>(nh, nl, wqt_h, wqt_l,
                                                                qh, ql, kh, kl, vt);
    if (split) {
        attn_chunk<<<dim3(64, HEADS), 1024, 0, stream>>>(qh, ql, kh, kl, vt,
                                                         po_dout, po_wqt, ml);
        attn_merge<<<dim3(SEQ / 64, HEADS), 256, 0, stream>>>(po_dout, po_wqt, ml, atto);
    } else {
        attn_mfma<<<dim3(SEQ / 64, HEADS), 256, 0, stream>>>(qh, ql, kh, kl, vt, atto);
    }
    gemm_out_256<<<dim3(DIM / 128, SEQ / 128), 512, 0, stream>>>(atto, wot, out);
}

// Round 17
// 241.707 us; speedup vs baseline: 1.1428x; 1.0950x over previous
//
#include <hip/hip_runtime.h>
#include <math.h>

#define SEQ 4096
#define DIM 1024
#define HEADS 8
#define DINNER 512
#define QKVW 1536
#define PAD 80   // LDS row stride (bf16 elems) for legacy fallback kernels
#define CHUNK 16 // K-tiles (of 64) per split-KV chunk

typedef unsigned short u16;
typedef __attribute__((ext_vector_type(8))) short s8v;   // 8 bf16 (4 VGPRs)
typedef __attribute__((ext_vector_type(4))) float f4v;   // 4 fp32 acc
#define MFMA(a, b, c) __builtin_amdgcn_mfma_f32_16x16x32_bf16(a, b, c, 0, 0, 0)

__device__ __forceinline__ u16 f2bf(float f) {
    unsigned u = __float_as_uint(f);
    u += 0x7fff + ((u >> 16) & 1);   // RNE
    return (u16)(u >> 16);
}
__device__ __forceinline__ float bf2f(u16 b) { return __uint_as_float(((unsigned)b) << 16); }

// async global->LDS, 16B per lane. LDS dest is wave-uniform base + lane*16 (HW rule);
// the GLOBAL source is per-lane and pre-swizzled to realize the LDS XOR swizzle (rule #21).
__device__ __forceinline__ void gload16(const u16* g, u16* l) {
    __builtin_amdgcn_global_load_lds(
        (const __attribute__((address_space(1))) unsigned int*)g,
        (__attribute__((address_space(3))) unsigned int*)l, 16, 0, 0);
}

// chunk-tile flat index: T = h*160 + base16(qt) + c; nc(qt) = qt/16 + 1
__device__ __forceinline__ int base16(int qt) {
    int a = qt >> 4, b = qt & 15;
    return 8 * a * (a + 1) + b * (a + 1);
}
// partials: tiles 0..1023 in d_out, 1024..1279 in the dead wqt region
__device__ __forceinline__ float* po_sel(int T, float* pd, float* pw) {
    return (T < 1024) ? pd + (size_t)T * 4096 : pw + (size_t)(T - 1024) * 4096;
}

// ---------- RMSNorm -> split bf16 (hi, lo), vectorized (G13) ----------
__global__ __launch_bounds__(256) void rmsnorm_split(const float* __restrict__ x,
                                                     const float* __restrict__ gamma,
                                                     u16* __restrict__ hi,
                                                     u16* __restrict__ lo) {
    __shared__ float red[4];
    const int row = blockIdx.x, t = threadIdx.x;
    const float4 xv = ((const float4*)(x + (size_t)row * DIM))[t];
    float ss = xv.x * xv.x + xv.y * xv.y + xv.z * xv.z + xv.w * xv.w;
#pragma unroll
    for (int off = 32; off >= 1; off >>= 1) ss += __shfl_xor(ss, off, 64);
    if ((t & 63) == 0) red[t >> 6] = ss;
    __syncthreads();
    float scale = 32.0f / fmaxf(sqrtf(red[0] + red[1] + red[2] + red[3]), 1e-12f);
    const float4 gv = ((const float4*)gamma)[t];
    float y[4] = {xv.x * scale * gv.x, xv.y * scale * gv.y,
                  xv.z * scale * gv.z, xv.w * scale * gv.w};
    unsigned hw0, hw1, lw0, lw1;
    {
        u16 h0 = f2bf(y[0]), h1 = f2bf(y[1]), h2 = f2bf(y[2]), h3 = f2bf(y[3]);
        hw0 = (unsigned)h0 | ((unsigned)h1 << 16);
        hw1 = (unsigned)h2 | ((unsigned)h3 << 16);
        lw0 = (unsigned)f2bf(y[0] - bf2f(h0)) | ((unsigned)f2bf(y[1] - bf2f(h1)) << 16);
        lw1 = (unsigned)f2bf(y[2] - bf2f(h2)) | ((unsigned)f2bf(y[3] - bf2f(h3)) << 16);
    }
    *(uint2*)&hi[(size_t)row * DIM + t * 4] = make_uint2(hw0, hw1);
    *(uint2*)&lo[(size_t)row * DIM + t * 4] = make_uint2(lw0, lw1);
}

// ---------- transpose fp32 [R][C] -> bf16 hi/lo [C][R] ----------
__global__ __launch_bounds__(256) void transpose_split(const float* __restrict__ in,
                                                       u16* __restrict__ hi,
                                                       u16* __restrict__ lo,
                                                       int R, int C, int want_lo) {
    __shared__ float tile[64][65];
    const int c0 = blockIdx.x * 64, r0 = blockIdx.y * 64;
    const int t = threadIdx.x, col = t & 63, rb = t >> 6;
#pragma unroll
    for (int j = 0; j < 16; ++j)
        tile[rb + j * 4][col] = in[(size_t)(r0 + rb + j * 4) * C + c0 + col];
    __syncthreads();
#pragma unroll
    for (int j = 0; j < 16; ++j) {
        int cc = rb + j * 4;
        float v = tile[col][cc];
        size_t oi = (size_t)(c0 + cc) * R + r0 + col;
        u16 h = f2bf(v);
        hi[oi] = h;
        if (want_lo) lo[oi] = f2bf(v - bf2f(h));
    }
}

// ---------- QKV GEMM: 128x96 tile, 512 blocks = EXACTLY 2/CU, gload_lds + XOR swizzle ----------
__global__ __launch_bounds__(256) void gemm_qkv_96(
    const u16* __restrict__ Ah, const u16* __restrict__ Al,
    const u16* __restrict__ Bh, const u16* __restrict__ Bl,
    u16* __restrict__ qh, u16* __restrict__ ql,
    u16* __restrict__ kh, u16* __restrict__ kl, u16* __restrict__ vtp) {
    __shared__ __align__(16) u16 AsH[128 * 64], AsL[128 * 64];
    __shared__ __align__(16) u16 BsH[96 * 64], BsL[96 * 64];
    const int t = threadIdx.x;
    const int bn = blockIdx.x * 96, bm = blockIdx.y * 128;
    const int w = t >> 6, lane = t & 63, m = lane & 15, q = lane >> 4;
    const int wr = w >> 1, wc = w & 1;   // 2(M) x 2(N) wave grid; wave = 64 x 48
    f4v acc[4][3];
#pragma unroll
    for (int i = 0; i < 4; ++i)
#pragma unroll
        for (int j = 0; j < 3; ++j) acc[i][j] = (f4v){0.f, 0.f, 0.f, 0.f};

    for (int k0 = 0; k0 < DIM; k0 += 64) {
        __syncthreads();
        // A: 128x64 = 1024 granules (4 passes); B: 96x64 = 768 granules (3 passes)
#pragma unroll
        for (int i = 0; i < 4; ++i) {
            int idx0 = i * 256 + w * 64;              // wave-uniform LDS granule base
            int row = (idx0 + lane) >> 3;
            int col = ((lane & 7) * 8) ^ ((row & 7) * 8);   // pre-swizzled source column
            gload16(&Ah[(size_t)(bm + row) * DIM + k0 + col], &AsH[idx0 * 8]);
            gload16(&Al[(size_t)(bm + row) * DIM + k0 + col], &AsL[idx0 * 8]);
            if (i < 3) {
                gload16(&Bh[(size_t)(bn + row) * DIM + k0 + col], &BsH[idx0 * 8]);
                gload16(&Bl[(size_t)(bn + row) * DIM + k0 + col], &BsL[idx0 * 8]);
            }
        }
        __syncthreads();   // compiler drains vmcnt(0) here
#pragma unroll
        for (int kk = 0; kk < 64; kk += 32) {
            s8v a_h[4], a_l[4], b_h[3], b_l[3];
#pragma unroll
            for (int f = 0; f < 4; ++f) {
                int ar = wr * 64 + f * 16 + m;
                int ab = ar * 128 + (((kk + q * 8) * 2) ^ ((ar & 7) << 4));
                a_h[f] = *(const s8v*)((const char*)AsH + ab);
                a_l[f] = *(const s8v*)((const char*)AsL + ab);
            }
#pragma unroll
            for (int f = 0; f < 3; ++f) {
                int br = wc * 48 + f * 16 + m;
                int bb = br * 128 + (((kk + q * 8) * 2) ^ ((br & 7) << 4));
                b_h[f] = *(const s8v*)((const char*)BsH + bb);
                b_l[f] = *(const s8v*)((const char*)BsL + bb);
            }
#pragma unroll
            for (int fm = 0; fm < 4; ++fm)
#pragma unroll
                for (int fn = 0; fn < 3; ++fn) {
                    acc[fm][fn] = MFMA(a_h[fm], b_h[fn], acc[fm][fn]);
                    acc[fm][fn] = MFMA(a_l[fm], b_h[fn], acc[fm][fn]);
                    acc[fm][fn] = MFMA(a_h[fm], b_l[fn], acc[fm][fn]);
                }
        }
    }
#pragma unroll
    for (int fm = 0; fm < 4; ++fm)
#pragma unroll
        for (int fn = 0; fn < 3; ++fn)
#pragma unroll
            for (int r = 0; r < 4; ++r) {
                int gr = bm + wr * 64 + fm * 16 + q * 4 + r;
                int gc = bn + wc * 48 + fn * 16 + m;
                float v = acc[fm][fn][r];
                int region = gc >> 9;   // per-element (boundary blocks straddle 512/1024)
                if (region == 0) {
                    v *= 8.0f;   // q * sqrt(d), faithful to reference
                    u16 h = f2bf(v);
                    qh[(size_t)gr * DINNER + gc] = h;
                    ql[(size_t)gr * DINNER + gc] = f2bf(v - bf2f(h));
                } else if (region == 1) {
                    u16 h = f2bf(v);
                    kh[(size_t)gr * DINNER + (gc - 512)] = h;
                    kl[(size_t)gr * DINNER + (gc - 512)] = f2bf(v - bf2f(h));
                } else {
                    vtp[(size_t)(gc - 1024) * SEQ + gr] = f2bf(v);
                }
            }
}

// ---------- split-KV flash attention: 16 waves/tile + WEIGHT-SORTED JOB MAPPING ----------
// 320 real jobs (no empty blocks). Job weight = iterations = {16 x224, 12 x32, 8 x32, 4 x32}.
// rank = bx<256 ? (bx+192)&255 : 575-bx spreads the weights so (assuming ~round-robin
// block->CU placement) every 2-job CU gets ~20-24 iters vs ~33 in the old qt4-major order
// (the measured makespan imbalance: avg CU work is 17 iters; Occ 20.9% showed idle CUs).
// Pure index permutation -- all (h,qt4,c)-derived logic and sync structure unchanged (R13).
__global__ __launch_bounds__(1024) void attn_chunk(
    const u16* __restrict__ qhp, const u16* __restrict__ qlp,
    const u16* __restrict__ kh, const u16* __restrict__ kl,
    const u16* __restrict__ vt,
    float* __restrict__ po_dout, float* __restrict__ po_wqt,
    float* __restrict__ ml) {
    __shared__ __align__(16) u16 KH[2][64 * 64], KL[2][64 * 64], VT[2][64 * 64];
    __shared__ __align__(16) u16 Pex[2][64 * 64];
    const int t = threadIdx.x;
    const int bx = blockIdx.x;
    const int rank = (bx < 256) ? ((bx + 192) & 255) : (575 - bx);
    int h, qt4, c;
    if (rank < 224) {          // full 16-iter jobs: per head 28 = 13(c0)+9(c1)+5(c2)+1(c3)
        h = rank / 28;
        int i = rank - h * 28;
        if (i < 13)      { c = 0; qt4 = 3 + i; }
        else if (i < 22) { c = 1; qt4 = 7 + (i - 13); }
        else if (i < 27) { c = 2; qt4 = 11 + (i - 22); }
        else             { c = 3; qt4 = 15; }
    } else if (rank < 256) {   // weight-12 jobs
        int idx = rank - 224; h = idx >> 2; c = idx & 3; qt4 = 4 * c + 2;
    } else if (rank < 288) {   // weight-8 jobs
        int idx = rank - 256; h = idx >> 2; c = idx & 3; qt4 = 4 * c + 1;
    } else {                   // weight-4 jobs
        int idx = rank - 288; h = idx >> 2; c = idx & 3; qt4 = 4 * c;
    }
    const int qtMax = 4 * qt4 + 3;
    const int kt0 = c * CHUNK;
    const int kt1 = (qtMax < kt0 + CHUNK - 1) ? qtMax : (kt0 + CHUNK - 1);
    const int w = t >> 6, lane = t & 63, m = lane & 15, g = lane >> 4;
    const int qt_w = 4 * qt4 + (w >> 2);   // this wave's 64-row q-tile
    const int wl = w & 3;                  // wave index within its q-tile

    // Q fragments in registers: row = qt_w*64 + wl*16 + m, d-cols g*8 (+0 / +32)
    const size_t qrow = (size_t)(qt_w * 64 + wl * 16 + m) * DINNER + h * 64;
    const s8v qf_h0 = *(const s8v*)&qhp[qrow + g * 8];
    const s8v qf_h1 = *(const s8v*)&qhp[qrow + 32 + g * 8];
    const s8v qf_l0 = *(const s8v*)&qlp[qrow + g * 8];
    const s8v qf_l1 = *(const s8v*)&qlp[qrow + 32 + g * 8];

    // staging (waves 0-7 only): 512 granules (16B) per 8KB tile, 1 gload per thread/array
    const int sg = w * 64;                 // wave-uniform granule base (w < 8)
    const int srow = (sg + lane) >> 3;
    const int sc = ((lane & 7) ^ (srow & 7)) * 8;   // pre-swizzled source col (elems)
    const bool stager = (w < 8);           // wave-uniform

    f4v o[4] = {{0.f, 0.f, 0.f, 0.f}, {0.f, 0.f, 0.f, 0.f},
                {0.f, 0.f, 0.f, 0.f}, {0.f, 0.f, 0.f, 0.f}};
    float mi_s = -1e30f, li_s = 0.f;   // per-lane stats for q-row wl*16 + m of qt_w

    // prologue: stage first tile into buf 0
    if (stager) {
        const u16* kr = &kh[(size_t)(kt0 * 64) * DINNER + h * 64];
        const u16* lr = &kl[(size_t)(kt0 * 64) * DINNER + h * 64];
        const u16* vr = &vt[(size_t)(h * 64) * SEQ + kt0 * 64];
        gload16(kr + (size_t)srow * DINNER + sc, &KH[0][sg * 8]);
        gload16(lr + (size_t)srow * DINNER + sc, &KL[0][sg * 8]);
        gload16(vr + (size_t)srow * SEQ + sc, &VT[0][sg * 8]);
    }
    __syncthreads();   // drains vmcnt(0)

    int cur = 0;
    for (int kt = kt0; kt <= kt1; ++kt) {
        if (stager && kt < kt1) {   // prefetch next tile into buf^1; drains at mid barrier
            int nb = cur ^ 1;
            const u16* kr = &kh[(size_t)((kt + 1) * 64) * DINNER + h * 64];
            const u16* lr = &kl[(size_t)((kt + 1) * 64) * DINNER + h * 64];
            const u16* vr = &vt[(size_t)(h * 64) * SEQ + (kt + 1) * 64];
            gload16(kr + (size_t)srow * DINNER + sc, &KH[nb][sg * 8]);
            gload16(lr + (size_t)srow * DINNER + sc, &KL[nb][sg * 8]);
            gload16(vr + (size_t)srow * SEQ + sc, &VT[nb][sg * 8]);
        }

        const bool act = (kt <= qt_w);   // wave-uniform; barriers stay outside
        f4v s[4] = {{0.f, 0.f, 0.f, 0.f}, {0.f, 0.f, 0.f, 0.f},
                    {0.f, 0.f, 0.f, 0.f}, {0.f, 0.f, 0.f, 0.f}};
        float alo[4];
        if (act) {
            // S^T: s[ct][r] = S[q = wl*16+m of qt_w][kv = ct*16+g*4+r]
            const char* KHc = (const char*)KH[cur];
            const char* KLc = (const char*)KL[cur];
            __builtin_amdgcn_s_setprio(1);
#pragma unroll
            for (int ct = 0; ct < 4; ++ct) {
                int rr = ct * 16 + m, rb = rr * 128, sw = (rr & 7) << 4;
                s8v bh0 = *(const s8v*)(KHc + rb + ((g * 16) ^ sw));
                s8v bl0 = *(const s8v*)(KLc + rb + ((g * 16) ^ sw));
                s[ct] = MFMA(bh0, qf_h0, s[ct]);
                s[ct] = MFMA(bh0, qf_l0, s[ct]);
                s[ct] = MFMA(bl0, qf_h0, s[ct]);
                s8v bh1 = *(const s8v*)(KHc + rb + ((64 + g * 16) ^ sw));
                s8v bl1 = *(const s8v*)(KLc + rb + ((64 + g * 16) ^ sw));
                s[ct] = MFMA(bh1, qf_h1, s[ct]);
                s[ct] = MFMA(bh1, qf_l1, s[ct]);
                s[ct] = MFMA(bl1, qf_h1, s[ct]);
            }
            __builtin_amdgcn_s_setprio(0);
            if (kt == qt_w) {   // causal: mask kv > q (tile-local)
#pragma unroll
                for (int ct = 0; ct < 4; ++ct)
#pragma unroll
                    for (int r = 0; r < 4; ++r)
                        if (ct * 16 + g * 4 + r > wl * 16 + m) s[ct][r] = -1e30f;
            }

            // lane-local online softmax (16 kv values per lane)
            float rm = -1e30f;
#pragma unroll
            for (int ct = 0; ct < 4; ++ct)
#pragma unroll
                for (int r = 0; r < 4; ++r) rm = fmaxf(rm, s[ct][r]);
            rm = fmaxf(rm, __shfl_xor(rm, 16, 64));
            rm = fmaxf(rm, __shfl_xor(rm, 32, 64));
            float mn = fmaxf(mi_s, rm);
            float al = __expf(mi_s - mn);
            mi_s = mn;
            float rs = 0.f;
#pragma unroll
            for (int ct = 0; ct < 4; ++ct)
#pragma unroll
                for (int r = 0; r < 4; ++r) {
                    s[ct][r] = __expf(s[ct][r] - mn);
                    rs += s[ct][r];
                }
            rs += __shfl_xor(rs, 16, 64);
            rs += __shfl_xor(rs, 32, 64);
            li_s = li_s * al + rs;
#pragma unroll
            for (int r = 0; r < 4; ++r) alo[r] = __shfl(al, g * 4 + r, 64);
        }

        __syncthreads();   // mid: all waves done reading K[cur]; prefetch drains here

        if (act) {
            // P: qtile 0 -> KH[cur], 1 -> KL[cur] (both dead), 2 -> Pex[0], 3 -> Pex[1]
            const int qtl = w >> 2;
            char* Pbuf = (char*)((qtl == 0) ? KH[cur] : (qtl == 1) ? KL[cur]
                                 : (qtl == 2) ? Pex[0] : Pex[1]);
            const int pr = wl * 16 + m, pb = pr * 128, psw = (m & 7) << 4;
#pragma unroll
            for (int ct = 0; ct < 4; ++ct) {
                unsigned w0 = (unsigned)f2bf(s[ct][0]) | ((unsigned)f2bf(s[ct][1]) << 16);
                unsigned w1 = (unsigned)f2bf(s[ct][2]) | ((unsigned)f2bf(s[ct][3]) << 16);
                *(uint2*)(Pbuf + pb + ((ct * 32 + g * 8) ^ psw)) = make_uint2(w0, w1);
            }
#pragma unroll
            for (int ct = 0; ct < 4; ++ct)
#pragma unroll
                for (int r = 0; r < 4; ++r) o[ct][r] *= alo[r];
            // PV: ap from own P rows (wave-private); bv from VT[cur] (swizzled)
            __builtin_amdgcn_s_setprio(1);
#pragma unroll
            for (int kk = 0; kk < 2; ++kk) {
                s8v ap = *(const s8v*)(Pbuf + pb + ((kk * 64 + g * 16) ^ psw));
#pragma unroll
                for (int ct = 0; ct < 4; ++ct) {
                    int vr2 = ct * 16 + m;
                    s8v bv = *(const s8v*)((const char*)VT[cur] + vr2 * 128 +
                                           ((kk * 64 + g * 16) ^ ((vr2 & 7) << 4)));
                    o[ct] = MFMA(ap, bv, o[ct]);
                }
            }
            __builtin_amdgcn_s_setprio(0);
        }

        __syncthreads();   // recycle: buf[cur] reads done before next iter's stage
        cur ^= 1;
    }

    // epilogue: raw partial o (fp32) + per-row (m, l) for this wave's q-tile
    const int T = h * 160 + base16(qt_w) + c;
    float* po = po_sel(T, po_dout, po_wqt);
#pragma unroll
    for (int ct = 0; ct < 4; ++ct)
#pragma unroll
        for (int r = 0; r < 4; ++r)
            po[(size_t)(wl * 16 + g * 4 + r) * 64 + ct * 16 + m] = o[ct][r];
    if (g == 0) {
        ml[(size_t)T * 128 + wl * 16 + m] = mi_s;
        ml[(size_t)T * 128 + 64 + wl * 16 + m] = li_s;
    }
}

// ---------- merge split-KV partials -> atto bf16 ----------
__global__ __launch_bounds__(256) void attn_merge(
    float* __restrict__ po_dout, float* __restrict__ po_wqt,
    const float* __restrict__ ml, u16* __restrict__ atto) {
    const int qt = blockIdx.x, h = blockIdx.y;
    const int nc = (qt >> 4) + 1;
    const int t = threadIdx.x, col = t & 63, rg = t >> 6;
    const int T0 = h * 160 + base16(qt);
    for (int j = 0; j < 16; ++j) {
        int row = rg * 16 + j;
        float mv[4], lv[4], M = -1e30f;
#pragma unroll 4
        for (int cc = 0; cc < 4; ++cc)
            if (cc < nc) {
                mv[cc] = ml[(size_t)(T0 + cc) * 128 + row];
                lv[cc] = ml[(size_t)(T0 + cc) * 128 + 64 + row];
                M = fmaxf(M, mv[cc]);
            }
        float acc = 0.f, den = 0.f;
#pragma unroll 4
        for (int cc = 0; cc < 4; ++cc)
            if (cc < nc) {
                const float* po = po_sel(T0 + cc, po_dout, po_wqt);
                float wg = __expf(mv[cc] - M);
                den += lv[cc] * wg;
                acc += wg * po[(size_t)row * 64 + col];
            }
        atto[(size_t)(qt * 64 + row) * DINNER + h * 64 + col] = f2bf(acc / den);
    }
}

// ---------- fallback: original fused flash attention (used if workspace too small) ----------
__global__ __launch_bounds__(256) void attn_mfma(
    const u16* __restrict__ qh, const u16* __restrict__ ql,
    const u16* __restrict__ kh, const u16* __restrict__ kl,
    const u16* __restrict__ vt, u16* __restrict__ atto) {
    __shared__ u16 Qh[64 * PAD], Ql[64 * PAD], KP[64 * PAD], Kl[64 * PAD], Vt[64 * PAD];
    const int t = threadIdx.x;
    const int qt = blockIdx.x, h = blockIdx.y;
    const int w = t >> 6, lane = t & 63, m = lane & 15, q = lane >> 4;

#pragma unroll
    for (int i = 0; i < 2; ++i) {
        int c = t + i * 256, row = c >> 3, ch = (c & 7) * 8;
        *(uint4*)&Qh[row * PAD + ch] =
            *(const uint4*)&qh[(size_t)(qt * 64 + row) * DINNER + h * 64 + ch];
        *(uint4*)&Ql[row * PAD + ch] =
            *(const uint4*)&ql[(size_t)(qt * 64 + row) * DINNER + h * 64 + ch];
    }

    f4v o[4] = {{0.f, 0.f, 0.f, 0.f}, {0.f, 0.f, 0.f, 0.f},
                {0.f, 0.f, 0.f, 0.f}, {0.f, 0.f, 0.f, 0.f}};
    float mi[4] = {-1e30f, -1e30f, -1e30f, -1e30f};
    float li[4] = {0.f, 0.f, 0.f, 0.f};

    for (int kt = 0; kt <= qt; ++kt) {
        __syncthreads();
#pragma unroll
        for (int i = 0; i < 2; ++i) {
            int c = t + i * 256, row = c >> 3, ch = (c & 7) * 8;
            *(uint4*)&KP[row * PAD + ch] =
                *(const uint4*)&kh[(size_t)(kt * 64 + row) * DINNER + h * 64 + ch];
            *(uint4*)&Kl[row * PAD + ch] =
                *(const uint4*)&kl[(size_t)(kt * 64 + row) * DINNER + h * 64 + ch];
            *(uint4*)&Vt[row * PAD + ch] =
                *(const uint4*)&vt[(size_t)(h * 64 + row) * SEQ + kt * 64 + ch];
        }
        __syncthreads();

        f4v s[4] = {{0.f, 0.f, 0.f, 0.f}, {0.f, 0.f, 0.f, 0.f},
                    {0.f, 0.f, 0.f, 0.f}, {0.f, 0.f, 0.f, 0.f}};
#pragma unroll
        for (int kk = 0; kk < 64; kk += 32) {
            s8v ah = *(const s8v*)&Qh[(w * 16 + m) * PAD + kk + q * 8];
            s8v al = *(const s8v*)&Ql[(w * 16 + m) * PAD + kk + q * 8];
#pragma unroll
            for (int ct = 0; ct < 4; ++ct) {
                s8v bh = *(const s8v*)&KP[(ct * 16 + m) * PAD + kk + q * 8];
                s8v bl = *(const s8v*)&Kl[(ct * 16 + m) * PAD + kk + q * 8];
                s[ct] = MFMA(ah, bh, s[ct]);
                s[ct] = MFMA(al, bh, s[ct]);
                s[ct] = MFMA(ah, bl, s[ct]);
            }
        }
        if (kt == qt) {
#pragma unroll
            for (int ct = 0; ct < 4; ++ct)
#pragma unroll
                for (int r = 0; r < 4; ++r)
                    if (ct * 16 + m > w * 16 + q * 4 + r) s[ct][r] = -1e30f;
        }

        float alpha[4];
#pragma unroll
        for (int r = 0; r < 4; ++r) {
            float rm = fmaxf(fmaxf(s[0][r], s[1][r]), fmaxf(s[2][r], s[3][r]));
#pragma unroll
            for (int off = 8; off >= 1; off >>= 1) rm = fmaxf(rm, __shfl_xor(rm, off, 64));
            float mn = fmaxf(mi[r], rm);
            alpha[r] = __expf(mi[r] - mn);
            mi[r] = mn;
            float rs = 0.f;
#pragma unroll
            for (int ct = 0; ct < 4; ++ct) {
                s[ct][r] = __expf(s[ct][r] - mn);
                rs += s[ct][r];
            }
#pragma unroll
            for (int off = 8; off >= 1; off >>= 1) rs += __shfl_xor(rs, off, 64);
            li[r] = li[r] * alpha[r] + rs;
        }

        __syncthreads();
#pragma unroll
        for (int ct = 0; ct < 4; ++ct)
#pragma unroll
            for (int r = 0; r < 4; ++r) {
                KP[(w * 16 + q * 4 + r) * PAD + ct * 16 + m] = f2bf(s[ct][r]);
                o[ct][r] *= alpha[r];
            }
#pragma unroll
        for (int kk = 0; kk < 64; kk += 32) {
            s8v ap = *(const s8v*)&KP[(w * 16 + m) * PAD + kk + q * 8];
#pragma unroll
            for (int ct = 0; ct < 4; ++ct) {
                s8v bv = *(const s8v*)&Vt[(ct * 16 + m) * PAD + kk + q * 8];
                o[ct] = MFMA(ap, bv, o[ct]);
            }
        }
    }

#pragma unroll
    for (int r = 0; r < 4; ++r) {
        float inv = 1.0f / li[r];
#pragma unroll
        for (int ct = 0; ct < 4; ++ct)
            atto[(size_t)(qt * 64 + w * 16 + q * 4 + r) * DINNER + h * 64 + ct * 16 + m] =
                f2bf(o[ct][r] * inv);
    }
}

// ---------- out projection: 128x128 tile, 512 thr, gload_lds + XOR swizzle ----------
// Grid (8,32) = 256 blocks = exactly 1/CU (perfect balance). 32KB LDS.
__global__ __launch_bounds__(512) void gemm_out_256(const u16* __restrict__ A,
                                                    const u16* __restrict__ Bt,
                                                    float* __restrict__ C) {
    __shared__ __align__(16) u16 As[128 * 64], Bs[128 * 64];
    const int t = threadIdx.x;
    const int bn = blockIdx.x * 128, bm = blockIdx.y * 128;
    const int w = t >> 6, lane = t & 63, m = lane & 15, q = lane >> 4;
    const int wr = w >> 2, wc = w & 3;   // 2(M) x 4(N)
    f4v acc[4][2];
#pragma unroll
    for (int i = 0; i < 4; ++i)
#pragma unroll
        for (int j = 0; j < 2; ++j) acc[i][j] = (f4v){0.f, 0.f, 0.f, 0.f};

    for (int k0 = 0; k0 < DINNER; k0 += 64) {
        __syncthreads();
#pragma unroll
        for (int i = 0; i < 2; ++i) {
            int idx0 = i * 512 + w * 64;
            int row = (idx0 + lane) >> 3;
            int col = ((lane & 7) * 8) ^ ((row & 7) * 8);
            gload16(&A[(size_t)(bm + row) * DINNER + k0 + col], &As[idx0 * 8]);
            gload16(&Bt[(size_t)(bn + row) * DINNER + k0 + col], &Bs[idx0 * 8]);
        }
        __syncthreads();
#pragma unroll
        for (int kk = 0; kk < 64; kk += 32) {
            s8v a_f[4], b_f[2];
#pragma unroll
            for (int f = 0; f < 4; ++f) {
                int ar = wr * 64 + f * 16 + m;
                a_f[f] = *(const s8v*)((const char*)As + ar * 128 +
                                       (((kk + q * 8) * 2) ^ ((ar & 7) << 4)));
            }
#pragma unroll
            for (int f = 0; f < 2; ++f) {
                int br = wc * 32 + f * 16 + m;
                b_f[f] = *(const s8v*)((const char*)Bs + br * 128 +
                                       (((kk + q * 8) * 2) ^ ((br & 7) << 4)));
            }
#pragma unroll
            for (int fm = 0; fm < 4; ++fm)
#pragma unroll
                for (int fn = 0; fn < 2; ++fn)
                    acc[fm][fn] = MFMA(a_f[fm], b_f[fn], acc[fm][fn]);
        }
    }
#pragma unroll
    for (int fm = 0; fm < 4; ++fm)
#pragma unroll
        for (int fn = 0; fn < 2; ++fn)
#pragma unroll
            for (int r = 0; r < 4; ++r)
                C[(size_t)(bm + wr * 64 + fm * 16 + q * 4 + r) * DIM +
                  bn + wc * 32 + fn * 16 + m] = acc[fm][fn][r];
}

extern "C" void kernel_launch(void* const* d_in, const int* in_sizes, int n_in,
                              void* d_out, int out_size, void* d_ws, size_t ws_size,
                              hipStream_t stream) {
    const float* x     = (const float*)d_in[0];
    const float* gamma = (const float*)d_in[1];
    const float* w_qkv = (const float*)d_in[2];
    const float* w_out = (const float*)d_in[3];
    float* out = (float*)d_out;

    // normed hi/lo live in d_out (exact fit; consumed by gemm_qkv before partials overwrite)
    u16* nh = (u16*)d_out;
    u16* nl = nh + (size_t)SEQ * DIM;

    u16* p = (u16*)d_ws;
    u16* wqt_h = p; p += (size_t)QKVW * DIM;
    u16* wqt_l = p; p += (size_t)QKVW * DIM;
    u16* wot   = p; p += (size_t)DIM * DINNER;
    u16* qh = p; p += (size_t)SEQ * DINNER;
    u16* ql = p; p += (size_t)SEQ * DINNER;
    u16* kh = p; p += (size_t)SEQ * DINNER;
    u16* kl = p; p += (size_t)SEQ * DINNER;
    u16* vt = p; p += (size_t)DINNER * SEQ;
    u16* atto = p; p += (size_t)SEQ * DINNER;

    // split-KV partials: 1280 chunk-tiles x 16KB fp32. Tiles 0..1023 in d_out (16.78MB),
    // 1024..1279 in the dead wqt_h/wqt_l region. ml in ws.
    float* po_dout = (float*)d_out;
    float* po_wqt  = (float*)wqt_h;
    float* ml      = (float*)p;
    const size_t need = (size_t)((char*)(ml + (size_t)1280 * 128) - (char*)d_ws);  // ~32 MB
    const bool split = ws_size >= need;

    transpose_split<<<dim3(QKVW / 64, DIM / 64), 256, 0, stream>>>(w_qkv, wqt_h, wqt_l,
                                                                   DIM, QKVW, 1);
    transpose_split<<<dim3(DIM / 64, DINNER / 64), 256, 0, stream>>>(w_out, wot, nullptr,
                                                                     DINNER, DIM, 0);
    rmsnorm_split<<<SEQ, 256, 0, stream>>>(x, gamma, nh, nl);
    gemm_qkv_96<<<dim3(QKVW / 96, SEQ / 128), 256, 0, stream>>>(nh, nl, wqt_h, wqt_l,
                                                                qh, ql, kh, kl, vt);
    if (split) {
        attn_chunk<<<dim3(320), 1024, 0, stream>>>(qh, ql, kh, kl, vt,
                                                   po_dout, po_wqt, ml);
        attn_merge<<<dim3(SEQ / 64, HEADS), 256, 0, stream>>>(po_dout, po_wqt, ml, atto);
    } else {
        attn_mfma<<<dim3(SEQ / 64, HEADS), 256, 0, stream>>>(qh, ql, kh, kl, vt, atto);
    }
    gemm_out_256<<<dim3(DIM / 128, SEQ / 128), 512, 0, stream>>>(atto, wot, out);
}